// Round 1
// 151.283 us; speedup vs baseline: 1.0256x; 1.0256x over previous
//
#include <hip/hip_runtime.h>

// Problem constants (fixed by the reference's setup_inputs)
constexpr int B = 32;
constexpr int L = 256;
constexpr int H = 512;
constexpr int HV = H / 4;   // 128 float4 per row
constexpr int CHUNK = 16;   // output t-rows per block (16 > 32: measured prev session)

// Fused kernel: per-block cumsum recompute + chunked expansion.
// grid = (ceil(T/CHUNK), B), block = 256 threads.
// R4 changes vs 155 µs baseline:
//  1. Hillis-Steele scan (16 barriers) -> shfl wave-scan + cross-wave combine
//     (2 barriers). Scan latency was serial prologue in every one of ~4128
//     blocks.
//  2. Register row-cache: idx is uniform per 128-lane half, so reload x only
//     when gidx changes (wave-uniform branch, no divergence). Cuts ~8
//     loads/thread to ~2-3 (avg duration 7.5 -> ~2-3 distinct rows/chunk).
// Plain stores (NT stores measured neutral-to-negative earlier).
__global__ __launch_bounds__(256) void lr_fused_kernel(
    const float4* __restrict__ x,   // (B, L, HV) float4
    const int* __restrict__ dur,    // (B, L)
    float4* __restrict__ out,       // (B, T, HV) float4
    float* __restrict__ mask,       // (B, T)
    int T) {
    __shared__ int sc[L];
    __shared__ int wsum[4];
    const int b = blockIdx.y;
    const int tid = threadIdx.x;    // 0..255
    const int lane64 = tid & 63;
    const int wid = tid >> 6;       // wave id 0..3

    // --- inclusive scan of durations for batch b: shfl within wave, ---
    // --- LDS combine across the 4 waves. 2 barriers total.          ---
    int s = dur[b * L + tid];
    #pragma unroll
    for (int off = 1; off < 64; off <<= 1) {
        int n = __shfl_up(s, off, 64);
        if (lane64 >= off) s += n;
    }
    if (lane64 == 63) wsum[wid] = s;
    __syncthreads();
    int woff = 0;
    if (wid > 0) woff += wsum[0];
    if (wid > 1) woff += wsum[1];
    if (wid > 2) woff += wsum[2];
    const int total = wsum[0] + wsum[1] + wsum[2] + wsum[3];
    sc[tid] = s + woff;
    __syncthreads();

    // --- expansion: two t-rows per iteration (halves of the block) ---
    const int t0 = blockIdx.x * CHUNK;
    const int half = tid >> 7;      // 0 or 1
    const int lane = tid & 127;     // float4 lane within the row

    // searchsorted(csum, t, 'right') for this half's first t: first idx with
    // sc[idx] > t. Uniform within each half -> LDS broadcast, no divergence.
    // For tfirst >= total this lands at idx == L, so the zero tail does no
    // LDS walking below.
    const int tfirst = t0 + half;
    int lo = 0, hi = L;
    while (lo < hi) {
        int mid = (lo + hi) >> 1;
        if (sc[mid] <= tfirst) lo = mid + 1; else hi = mid;
    }
    int idx = lo;   // in [0, L]

    int cur = -1;                    // cached source row (uniform per half)
    float4 val = make_float4(0.f, 0.f, 0.f, 0.f);

    #pragma unroll
    for (int i = 0; i < CHUNK / 2; ++i) {
        const int t = t0 + 2 * i + half;
        // monotone advance (t increases by 2 per iter; ~2 total advances/chunk)
        while (idx < L && sc[idx] <= t) ++idx;
        if (t < T) {
            float4 o = make_float4(0.f, 0.f, 0.f, 0.f);
            if (t < total) {
                const int gidx = (idx < L - 1) ? idx : (L - 1);  // clip to L-1
                if (gidx != cur) {           // wave-uniform reload
                    val = x[((size_t)(b * L + gidx)) * HV + lane];
                    cur = gidx;
                }
                o = val;
            }
            out[((size_t)b * T + t) * HV + lane] = o;
        }
    }

    // --- mask: 16 consecutive floats per block, coalesced ---
    if (tid < CHUNK) {
        const int t = t0 + tid;
        if (t < T) {
            mask[(size_t)b * T + t] = (t < total) ? 1.0f : 0.0f;
        }
    }
}

extern "C" void kernel_launch(void* const* d_in, const int* in_sizes, int n_in,
                              void* d_out, int out_size, void* d_ws, size_t ws_size,
                              hipStream_t stream) {
    const float* x = (const float*)d_in[0];       // (B, L, H) fp32
    const int* dur = (const int*)d_in[1];         // (B, L) int32
    float* out = (float*)d_out;

    // out_size = B*T*H + B*T = B*T*(H+1)  ->  T
    const int T = out_size / (B * (H + 1));

    float* mask_out = out + (size_t)B * T * H;
    dim3 grid((T + CHUNK - 1) / CHUNK, B);
    lr_fused_kernel<<<grid, 256, 0, stream>>>((const float4*)x, dur,
                                              (float4*)out, mask_out, T);
}

// Round 2
// 150.324 us; speedup vs baseline: 1.0321x; 1.0064x over previous
//
#include <hip/hip_runtime.h>

// Problem constants (fixed by the reference's setup_inputs)
constexpr int B = 32;
constexpr int L = 256;
constexpr int H = 512;
constexpr int HV = H / 4;   // 128 float4 per row
constexpr int CHUNK = 16;   // output t-rows per block (16 > 32: measured prev session)

// Fused kernel: per-block cumsum recompute + chunked expansion.
// grid = (ceil(T/CHUNK), B), block = 256 threads.
// R5 change vs R4 (151.3 us): break the store loop's serial dependency chain.
//   R4: each of 8 iterations did a DEPENDENT LDS walk (while sc[idx]<=t,
//       ~120cyc latency each) + carried row-cache -> stores issue behind an
//       8-step latency chain.
//   R5: 16 threads binary-search all CHUNK row indices in parallel into
//       sidx[] (one extra barrier), then 8 independent LDS reads -> 8
//       independent x loads (x is L2/L3-resident; redundant loads at 34.5TB/s
//       beat a serial chain) -> 8 independent stores. Full MLP.
// Plain stores (NT stores measured neutral-to-negative earlier).
__global__ __launch_bounds__(256) void lr_fused_kernel(
    const float4* __restrict__ x,   // (B, L, HV) float4
    const int* __restrict__ dur,    // (B, L)
    float4* __restrict__ out,       // (B, T, HV) float4
    float* __restrict__ mask,       // (B, T)
    int T) {
    __shared__ int sc[L];
    __shared__ int wsum[4];
    __shared__ int sidx[CHUNK];
    const int b = blockIdx.y;
    const int tid = threadIdx.x;    // 0..255
    const int lane64 = tid & 63;
    const int wid = tid >> 6;       // wave id 0..3

    // --- inclusive scan of durations for batch b: shfl within wave, ---
    // --- LDS combine across the 4 waves. 2 barriers.                ---
    int s = dur[b * L + tid];
    #pragma unroll
    for (int off = 1; off < 64; off <<= 1) {
        int n = __shfl_up(s, off, 64);
        if (lane64 >= off) s += n;
    }
    if (lane64 == 63) wsum[wid] = s;
    __syncthreads();
    int woff = 0;
    if (wid > 0) woff += wsum[0];
    if (wid > 1) woff += wsum[1];
    if (wid > 2) woff += wsum[2];
    const int total = wsum[0] + wsum[1] + wsum[2] + wsum[3];
    sc[tid] = s + woff;
    __syncthreads();

    // --- per-row source index: 16 parallel binary searches ---
    // searchsorted(csum, t, 'right'): first idx with sc[idx] > t, clipped to
    // L-1. For t >= total this clips to L-1 (valid address; output zeroed
    // below). Mask write folded in here to overlap with the searches.
    const int t0 = blockIdx.x * CHUNK;
    if (tid < CHUNK) {
        const int t = t0 + tid;
        int lo = 0, hi = L;
        while (lo < hi) {
            int mid = (lo + hi) >> 1;
            if (sc[mid] <= t) lo = mid + 1; else hi = mid;
        }
        sidx[tid] = (lo < L - 1) ? lo : (L - 1);
        if (t < T) {
            mask[(size_t)b * T + t] = (t < total) ? 1.0f : 0.0f;
        }
    }
    __syncthreads();

    // --- expansion: two t-rows per iteration (halves of the block), ---
    // --- all 8 iterations fully independent.                        ---
    const int half = tid >> 7;      // 0 or 1
    const int lane = tid & 127;     // float4 lane within the row

    int g[CHUNK / 2];
    #pragma unroll
    for (int i = 0; i < CHUNK / 2; ++i) {
        g[i] = sidx[2 * i + half];  // independent LDS reads
    }

    const size_t xbase = (size_t)b * L * HV + lane;
    float4 v[CHUNK / 2];
    #pragma unroll
    for (int i = 0; i < CHUNK / 2; ++i) {
        v[i] = x[xbase + (size_t)g[i] * HV];   // independent, L2/L3-resident
    }

    const size_t obase = ((size_t)b * T + t0 + half) * HV + lane;
    #pragma unroll
    for (int i = 0; i < CHUNK / 2; ++i) {
        const int t = t0 + 2 * i + half;
        if (t < T) {
            float4 o = make_float4(0.f, 0.f, 0.f, 0.f);
            if (t < total) o = v[i];
            out[obase + (size_t)(2 * i) * HV] = o;
        }
    }
}

extern "C" void kernel_launch(void* const* d_in, const int* in_sizes, int n_in,
                              void* d_out, int out_size, void* d_ws, size_t ws_size,
                              hipStream_t stream) {
    const float* x = (const float*)d_in[0];       // (B, L, H) fp32
    const int* dur = (const int*)d_in[1];         // (B, L) int32
    float* out = (float*)d_out;

    // out_size = B*T*H + B*T = B*T*(H+1)  ->  T
    const int T = out_size / (B * (H + 1));

    float* mask_out = out + (size_t)B * T * H;
    dim3 grid((T + CHUNK - 1) / CHUNK, B);
    lr_fused_kernel<<<grid, 256, 0, stream>>>((const float4*)x, dur,
                                              (float4*)out, mask_out, T);
}